// Round 4
// baseline (611.341 us; speedup 1.0000x reference)
//
#include <hip/hip_runtime.h>

#define B_ 4
#define T_ 2048
#define D_ 1024
#define H_ 16
#define DK_ 64
#define M_ (B_*T_)   // 8192 rows

typedef __bf16 bf16;
typedef __bf16 bf16x8 __attribute__((ext_vector_type(8)));
typedef float f32x4 __attribute__((ext_vector_type(4)));

__device__ __forceinline__ f32x4 zero4() { f32x4 v = {0.f, 0.f, 0.f, 0.f}; return v; }

// ---------------- fp32 -> bf16 cast (x) ----------------
__global__ __launch_bounds__(256) void conv_bf16(const float* __restrict__ src,
                                                 bf16* __restrict__ dst) {
  const size_t i = (size_t)blockIdx.x * 256 + threadIdx.x;  // 8 elements per thread
  const float4 a = ((const float4*)src)[i * 2];
  const float4 b = ((const float4*)src)[i * 2 + 1];
  bf16x8 o;
  o[0] = (bf16)a.x; o[1] = (bf16)a.y; o[2] = (bf16)a.z; o[3] = (bf16)a.w;
  o[4] = (bf16)b.x; o[5] = (bf16)b.y; o[6] = (bf16)b.z; o[7] = (bf16)b.w;
  *(bf16x8*)(dst + i * 8) = o;
}

// ---------------- weight transpose + cast: dst[C][R] = (bf16)src[R][C] ----------------
__global__ __launch_bounds__(256) void transpose_wf(const float* __restrict__ src,
                                                    bf16* __restrict__ dst, int R, int C) {
  __shared__ alignas(16) bf16 ts[64 * 65];
  const int tid = threadIdx.x;
  const int r0 = blockIdx.x * 64, c0 = blockIdx.y * 64;
  {
    int rr = tid >> 2, cc = (tid & 3) * 16;
    const float4* p4 = (const float4*)(src + (size_t)(r0 + rr) * C + c0 + cc);
    float fv[16];
#pragma unroll
    for (int q = 0; q < 4; ++q) *(float4*)&fv[q * 4] = p4[q];
#pragma unroll
    for (int i = 0; i < 16; ++i) ts[(cc + i) * 65 + rr] = (bf16)fv[i];
  }
  __syncthreads();
  {
    int rr = tid >> 2, cc = (tid & 3) * 16;
    bf16x8 a, b;
#pragma unroll
    for (int i = 0; i < 8; ++i) a[i] = ts[rr * 65 + cc + i];
#pragma unroll
    for (int i = 0; i < 8; ++i) b[i] = ts[rr * 65 + cc + 8 + i];
    bf16* q = dst + (size_t)(c0 + rr) * R + r0 + cc;
    *(bf16x8*)q = a;
    *(bf16x8*)(q + 8) = b;
  }
}

// ---------------- GEMM: C[M][N] = A[M][K] @ Bt[N][K]^T + bias ----------------
// Register staging + ds_write_b128. bias fp32.
// FUSE=false: store bf16 C.  FUSE=true: Cf32 = C + resid(fp32).
template <bool FUSE>
__global__ __launch_bounds__(256) void gemm128(const bf16* __restrict__ A,
                                               const bf16* __restrict__ Bt,
                                               const float* __restrict__ bias,
                                               bf16* __restrict__ Cbf,
                                               float* __restrict__ Cf,
                                               const float* __restrict__ resid,
                                               int N, int K) {
  __shared__ alignas(16) bf16 As[128 * 32];
  __shared__ alignas(16) bf16 Bs[128 * 32];
  const int tid = threadIdx.x;
  const int wid = tid >> 6, lane = tid & 63, quad = lane >> 4, l16 = lane & 15;
  const int m0 = blockIdx.x * 128, n0 = blockIdx.y * 128;
  const int wr = (wid >> 1) * 64, wc = (wid & 1) * 64;

  f32x4 acc[4][4];
#pragma unroll
  for (int i = 0; i < 4; ++i)
#pragma unroll
    for (int j = 0; j < 4; ++j) acc[i][j] = zero4();

  for (int k0 = 0; k0 < K; k0 += 32) {
    bf16x8 ar[2], br[2];
#pragma unroll
    for (int p = 0; p < 2; ++p) {
      int t = p * 256 + tid;
      int row = t >> 2, kc = (t & 3) * 8;
      ar[p] = *(const bf16x8*)(A + (size_t)(m0 + row) * K + k0 + kc);
      br[p] = *(const bf16x8*)(Bt + (size_t)(n0 + row) * K + k0 + kc);
    }
    __syncthreads();  // previous iteration's LDS reads complete
#pragma unroll
    for (int p = 0; p < 2; ++p) {
      int t = p * 256 + tid;
      int row = t >> 2, kc = (t & 3) * 8;
      *(bf16x8*)&As[row * 32 + kc] = ar[p];
      *(bf16x8*)&Bs[row * 32 + kc] = br[p];
    }
    __syncthreads();
    bf16x8 af[4], bfr[4];
#pragma unroll
    for (int i = 0; i < 4; ++i)
      af[i] = *(const bf16x8*)&As[(wr + i * 16 + l16) * 32 + quad * 8];
#pragma unroll
    for (int j = 0; j < 4; ++j)
      bfr[j] = *(const bf16x8*)&Bs[(wc + j * 16 + l16) * 32 + quad * 8];
#pragma unroll
    for (int i = 0; i < 4; ++i)
#pragma unroll
      for (int j = 0; j < 4; ++j)
        acc[i][j] = __builtin_amdgcn_mfma_f32_16x16x32_bf16(af[i], bfr[j], acc[i][j], 0, 0, 0);
  }

#pragma unroll
  for (int i = 0; i < 4; ++i) {
#pragma unroll
    for (int j = 0; j < 4; ++j) {
      const int col = n0 + wc + j * 16 + l16;
      const float bv = bias[col];
#pragma unroll
      for (int r = 0; r < 4; ++r) {
        const int row = m0 + wr + i * 16 + quad * 4 + r;
        const size_t off = (size_t)row * N + col;
        const float v = acc[i][j][r] + bv;
        if (FUSE) Cf[off] = v + resid[off];
        else      Cbf[off] = (bf16)v;
      }
    }
  }
}

// ---------------- flash attention: block = (b, h, 64 q-rows), 4 waves x 16 rows ----------------
__global__ __launch_bounds__(256) void attn64(const bf16* __restrict__ qkv,
                                              bf16* __restrict__ out) {
  __shared__ alignas(16) bf16 Ks[128 * 64];      // [key][f]
  __shared__ alignas(16) bf16 Vs[64 * 128];      // [f][key]  (V^T tile)
  __shared__ alignas(16) bf16 Ps[4 * 16 * 136];  // per-wave P [16][128], stride 136 (pad)
  const int tid = threadIdx.x;
  const int wid = tid >> 6, lane = tid & 63, quad = lane >> 4, l16 = lane & 15;
  int bid = blockIdx.x;
  const int qb = bid & 31; bid >>= 5;
  const int h = bid & 15;  const int b = bid >> 4;
  const int q0 = qb * 64;

  // Q fragments (A-operand layout: m=lane&15, k=quad*8+j), 2 k-steps of 32
  bf16x8 qf[2];
  {
    const bf16* qp = qkv + (size_t)(b * T_ + q0 + wid * 16 + l16) * (3 * D_) + h * DK_ + quad * 8;
    qf[0] = *(const bf16x8*)qp;
    qf[1] = *(const bf16x8*)(qp + 32);
  }

  float mi[4], li[4];
  f32x4 o[4];
#pragma unroll
  for (int r = 0; r < 4; ++r) { mi[r] = -1e30f; li[r] = 0.f; }
#pragma unroll
  for (int ft = 0; ft < 4; ++ft) o[ft] = zero4();

  for (int kt = 0; kt < T_ / 128; ++kt) {
    __syncthreads();
#pragma unroll
    for (int p = 0; p < 4; ++p) {
      int t = p * 256 + tid;            // [0,1024): 128 keys x 8 f-chunks
      int key = t >> 3, f = (t & 7) * 8;
      const bf16* rowp = qkv + (size_t)(b * T_ + kt * 128 + key) * (3 * D_) + h * DK_ + f;
      bf16x8 kv = *(const bf16x8*)(rowp + D_);       // K columns
      *(bf16x8*)&Ks[key * 64 + f] = kv;
      bf16x8 vv = *(const bf16x8*)(rowp + 2 * D_);   // V columns
#pragma unroll
      for (int i = 0; i < 8; ++i) Vs[(f + i) * 128 + key] = vv[i];  // transpose in LDS
    }
    __syncthreads();

    // S = scale * Q K^T : per wave 16 x 128
    f32x4 sv[8];
#pragma unroll
    for (int nt = 0; nt < 8; ++nt) sv[nt] = zero4();
#pragma unroll
    for (int nt = 0; nt < 8; ++nt)
#pragma unroll
      for (int ks = 0; ks < 2; ++ks) {
        bf16x8 kf = *(const bf16x8*)&Ks[(nt * 16 + l16) * 64 + ks * 32 + quad * 8];
        sv[nt] = __builtin_amdgcn_mfma_f32_16x16x32_bf16(qf[ks], kf, sv[nt], 0, 0, 0);
      }

    // online softmax per row (row = quad*4 + r, cols spread over 16 lanes of the quad)
    float alpha[4];
#pragma unroll
    for (int r = 0; r < 4; ++r) {
      float tmax = -1e30f;
#pragma unroll
      for (int nt = 0; nt < 8; ++nt) { sv[nt][r] *= 0.125f; tmax = fmaxf(tmax, sv[nt][r]); }
#pragma unroll
      for (int m = 1; m < 16; m <<= 1) tmax = fmaxf(tmax, __shfl_xor(tmax, m, 64));
      const float mnew = fmaxf(mi[r], tmax);
      alpha[r] = __expf(mi[r] - mnew);
      float s = 0.f;
#pragma unroll
      for (int nt = 0; nt < 8; ++nt) {
        float pe = __expf(sv[nt][r] - mnew);
        sv[nt][r] = pe; s += pe;
      }
#pragma unroll
      for (int m = 1; m < 16; m <<= 1) s += __shfl_xor(s, m, 64);
      li[r] = li[r] * alpha[r] + s;
      mi[r] = mnew;
#pragma unroll
      for (int ft = 0; ft < 4; ++ft) o[ft][r] *= alpha[r];
    }

    // P: C-layout -> A-layout via LDS (per-wave private region)
#pragma unroll
    for (int nt = 0; nt < 8; ++nt)
#pragma unroll
      for (int r = 0; r < 4; ++r)
        Ps[wid * 2176 + (quad * 4 + r) * 136 + nt * 16 + l16] = (bf16)sv[nt][r];
    __syncthreads();

    // O += P @ V  (B-operand from Vs = V^T tile)
#pragma unroll
    for (int ks2 = 0; ks2 < 4; ++ks2) {
      bf16x8 pf = *(const bf16x8*)&Ps[wid * 2176 + l16 * 136 + ks2 * 32 + quad * 8];
#pragma unroll
      for (int ft = 0; ft < 4; ++ft) {
        bf16x8 vfr = *(const bf16x8*)&Vs[(ft * 16 + l16) * 128 + ks2 * 32 + quad * 8];
        o[ft] = __builtin_amdgcn_mfma_f32_16x16x32_bf16(pf, vfr, o[ft], 0, 0, 0);
      }
    }
  }

#pragma unroll
  for (int r = 0; r < 4; ++r) {
    const float inv = 1.0f / li[r];
    const int row = b * T_ + q0 + wid * 16 + quad * 4 + r;
#pragma unroll
    for (int ft = 0; ft < 4; ++ft)
      out[(size_t)row * D_ + h * DK_ + ft * 16 + l16] = (bf16)(o[ft][r] * inv);
  }
}

// ---------------- layernorm: one block per row (all fp32) ----------------
__global__ __launch_bounds__(256) void ln_out(const float* __restrict__ res,
                                              const float* __restrict__ gamma,
                                              const float* __restrict__ beta,
                                              float* __restrict__ out) {
  const int row = blockIdx.x;
  const int tid = threadIdx.x;
  const float4 v = *(const float4*)(res + (size_t)row * D_ + tid * 4);
  float s = v.x + v.y + v.z + v.w;
  float q = v.x * v.x + v.y * v.y + v.z * v.z + v.w * v.w;
#pragma unroll
  for (int m = 1; m < 64; m <<= 1) { s += __shfl_xor(s, m, 64); q += __shfl_xor(q, m, 64); }
  __shared__ float rs_[4], rq_[4];
  const int wid = tid >> 6, lane = tid & 63;
  if (lane == 0) { rs_[wid] = s; rq_[wid] = q; }
  __syncthreads();
  s = rs_[0] + rs_[1] + rs_[2] + rs_[3];
  q = rq_[0] + rq_[1] + rq_[2] + rq_[3];
  const float mu = s * (1.0f / D_);
  const float var = q * (1.0f / D_) - mu * mu;
  const float rstd = rsqrtf(var + 1e-5f);
  const float* vp = (const float*)&v;
  float4 ov;
  float* ovp = (float*)&ov;
#pragma unroll
  for (int i = 0; i < 4; ++i) {
    const int c = tid * 4 + i;
    ovp[i] = ((vp[i] - mu) * rstd) * gamma[c] + beta[c];
  }
  *(float4*)(out + (size_t)row * D_ + tid * 4) = ov;
}

extern "C" void kernel_launch(void* const* d_in, const int* in_sizes, int n_in,
                              void* d_out, int out_size, void* d_ws, size_t ws_size,
                              hipStream_t stream) {
  const float* x     = (const float*)d_in[0];
  const float* Wqkv  = (const float*)d_in[1];
  const float* bqkv  = (const float*)d_in[2];
  const float* Wout  = (const float*)d_in[3];
  const float* bout  = (const float*)d_in[4];
  const float* gamma = (const float*)d_in[5];
  const float* beta  = (const float*)d_in[6];
  float* out = (float*)d_out;

  // workspace layout (75.5 MB total):
  char* ws = (char*)d_ws;
  bf16* xb    = (bf16*)ws; ws += (size_t)M_ * D_ * 2;            // [8192][1024]  16.8 MB
  bf16* WqkvT = (bf16*)ws; ws += (size_t)3 * D_ * D_ * 2;        // [3072][1024]   6.3 MB
  bf16* WoutT = (bf16*)ws; ws += (size_t)D_ * D_ * 2;            // [1024][1024]   2.1 MB
  bf16* qkv   = (bf16*)ws;                                       // [8192][3072]  50.3 MB
  bf16* attn  = xb;           // alias: xb dead after qkv GEMM
  float* res  = (float*)qkv;  // alias: qkv dead after attn64; 33.6 <= 50.3 MB

  conv_bf16<<<M_ * D_ / (256 * 8), 256, 0, stream>>>(x, xb);
  transpose_wf<<<dim3(D_ / 64, 3 * D_ / 64), 256, 0, stream>>>(Wqkv, WqkvT, D_, 3 * D_);
  transpose_wf<<<dim3(D_ / 64, D_ / 64), 256, 0, stream>>>(Wout, WoutT, D_, D_);
  gemm128<false><<<dim3(M_ / 128, 3 * D_ / 128), 256, 0, stream>>>(
      xb, WqkvT, bqkv, qkv, nullptr, nullptr, 3 * D_, D_);
  attn64<<<B_ * H_ * (T_ / 64), 256, 0, stream>>>(qkv, attn);
  gemm128<true><<<dim3(M_ / 128, D_ / 128), 256, 0, stream>>>(
      attn, WoutT, bout, nullptr, res, x, D_, D_);
  ln_out<<<M_, 256, 0, stream>>>(res, gamma, beta, out);
}

// Round 5
// 482.355 us; speedup vs baseline: 1.2674x; 1.2674x over previous
//
#include <hip/hip_runtime.h>

#define B_ 4
#define T_ 2048
#define D_ 1024
#define H_ 16
#define DK_ 64
#define M_ (B_*T_)   // 8192 rows

typedef __bf16 bf16;
typedef __bf16 bf16x8 __attribute__((ext_vector_type(8)));
typedef float f32x4 __attribute__((ext_vector_type(4)));

__device__ __forceinline__ f32x4 zero4() { f32x4 v = {0.f, 0.f, 0.f, 0.f}; return v; }

// ---------------- weight transpose + cast: dst[C][R] = (bf16)src[R][C] ----------------
__global__ __launch_bounds__(256) void transpose_wf(const float* __restrict__ src,
                                                    bf16* __restrict__ dst, int R, int C) {
  __shared__ alignas(16) bf16 ts[64 * 65];
  const int tid = threadIdx.x;
  const int r0 = blockIdx.x * 64, c0 = blockIdx.y * 64;
  {
    int rr = tid >> 2, cc = (tid & 3) * 16;
    const float4* p4 = (const float4*)(src + (size_t)(r0 + rr) * C + c0 + cc);
    float fv[16];
#pragma unroll
    for (int q = 0; q < 4; ++q) *(float4*)&fv[q * 4] = p4[q];
#pragma unroll
    for (int i = 0; i < 16; ++i) ts[(cc + i) * 65 + rr] = (bf16)fv[i];
  }
  __syncthreads();
  {
    int rr = tid >> 2, cc = (tid & 3) * 16;
    bf16x8 a, b;
#pragma unroll
    for (int i = 0; i < 8; ++i) a[i] = ts[rr * 65 + cc + i];
#pragma unroll
    for (int i = 0; i < 8; ++i) b[i] = ts[rr * 65 + cc + 8 + i];
    bf16* q = dst + (size_t)(c0 + rr) * R + r0 + cc;
    *(bf16x8*)q = a;
    *(bf16x8*)(q + 8) = b;
  }
}

// ---------------- V transpose: Vt[b][h][f][t] = qkv[b*T+t][2D + h*64 + f] ----------------
__global__ __launch_bounds__(256) void transpose_v(const bf16* __restrict__ qkv,
                                                   bf16* __restrict__ Vt) {
  __shared__ alignas(16) bf16 ts[64 * 65];
  int bid = blockIdx.x;
  const int tt = bid & 31; bid >>= 5;
  const int h = bid & 15;  const int b = bid >> 4;
  const int t0 = tt * 64;
  const int tid = threadIdx.x;
  {
    int tok = tid >> 2, fc = (tid & 3) * 16;
    const bf16* p = qkv + (size_t)(b * T_ + t0 + tok) * (3 * D_) + 2 * D_ + h * DK_ + fc;
    bf16x8 a = *(const bf16x8*)p;
    bf16x8 c = *(const bf16x8*)(p + 8);
#pragma unroll
    for (int i = 0; i < 8; ++i) ts[(fc + i) * 65 + tok] = a[i];
#pragma unroll
    for (int i = 0; i < 8; ++i) ts[(fc + 8 + i) * 65 + tok] = c[i];
  }
  __syncthreads();
  {
    int f = tid >> 2, tc = (tid & 3) * 16;
    bf16x8 a, c;
#pragma unroll
    for (int i = 0; i < 8; ++i) a[i] = ts[f * 65 + tc + i];
#pragma unroll
    for (int i = 0; i < 8; ++i) c[i] = ts[f * 65 + tc + 8 + i];
    bf16* q = Vt + ((size_t)(b * H_ + h) * DK_ + f) * T_ + t0 + tc;
    *(bf16x8*)q = a;
    *(bf16x8*)(q + 8) = c;
  }
}

// ---------------- GEMM: C[M][N] = A[M][K] @ Bt[N][K]^T + bias ----------------
// AF32: A is fp32, cast to bf16 during staging. lda = A row stride (elements).
// FUSE=false: store bf16 C (row stride ldc). FUSE=true: Cf32 = C + resid(fp32), stride N.
template <bool AF32, bool FUSE>
__global__ __launch_bounds__(256) void gemm128(const void* __restrict__ Av,
                                               const bf16* __restrict__ Bt,
                                               const float* __restrict__ bias,
                                               bf16* __restrict__ Cbf,
                                               float* __restrict__ Cf,
                                               const float* __restrict__ resid,
                                               int N, int K, int lda, int ldc) {
  __shared__ alignas(16) bf16 As[128 * 32];
  __shared__ alignas(16) bf16 Bs[128 * 32];
  const int tid = threadIdx.x;
  const int wid = tid >> 6, lane = tid & 63, quad = lane >> 4, l16 = lane & 15;
  const int m0 = blockIdx.x * 128, n0 = blockIdx.y * 128;
  const int wr = (wid >> 1) * 64, wc = (wid & 1) * 64;

  f32x4 acc[4][4];
#pragma unroll
  for (int i = 0; i < 4; ++i)
#pragma unroll
    for (int j = 0; j < 4; ++j) acc[i][j] = zero4();

  for (int k0 = 0; k0 < K; k0 += 32) {
    bf16x8 ar[2], br[2];
#pragma unroll
    for (int p = 0; p < 2; ++p) {
      int t = p * 256 + tid;
      int row = t >> 2, kc = (t & 3) * 8;
      if (AF32) {
        const float* ap = (const float*)Av + (size_t)(m0 + row) * lda + k0 + kc;
        float4 a0 = *(const float4*)ap, a1 = *(const float4*)(ap + 4);
        bf16x8 v;
        v[0] = (bf16)a0.x; v[1] = (bf16)a0.y; v[2] = (bf16)a0.z; v[3] = (bf16)a0.w;
        v[4] = (bf16)a1.x; v[5] = (bf16)a1.y; v[6] = (bf16)a1.z; v[7] = (bf16)a1.w;
        ar[p] = v;
      } else {
        ar[p] = *(const bf16x8*)((const bf16*)Av + (size_t)(m0 + row) * lda + k0 + kc);
      }
      br[p] = *(const bf16x8*)(Bt + (size_t)(n0 + row) * K + k0 + kc);
    }
    __syncthreads();  // previous iteration's LDS reads complete
#pragma unroll
    for (int p = 0; p < 2; ++p) {
      int t = p * 256 + tid;
      int row = t >> 2, kc = (t & 3) * 8;
      *(bf16x8*)&As[row * 32 + kc] = ar[p];
      *(bf16x8*)&Bs[row * 32 + kc] = br[p];
    }
    __syncthreads();
    bf16x8 af[4], bfr[4];
#pragma unroll
    for (int i = 0; i < 4; ++i)
      af[i] = *(const bf16x8*)&As[(wr + i * 16 + l16) * 32 + quad * 8];
#pragma unroll
    for (int j = 0; j < 4; ++j)
      bfr[j] = *(const bf16x8*)&Bs[(wc + j * 16 + l16) * 32 + quad * 8];
#pragma unroll
    for (int i = 0; i < 4; ++i)
#pragma unroll
      for (int j = 0; j < 4; ++j)
        acc[i][j] = __builtin_amdgcn_mfma_f32_16x16x32_bf16(af[i], bfr[j], acc[i][j], 0, 0, 0);
  }

#pragma unroll
  for (int i = 0; i < 4; ++i) {
#pragma unroll
    for (int j = 0; j < 4; ++j) {
      const int col = n0 + wc + j * 16 + l16;
      const float bv = bias[col];
#pragma unroll
      for (int r = 0; r < 4; ++r) {
        const int row = m0 + wr + i * 16 + quad * 4 + r;
        const float v = acc[i][j][r] + bv;
        if (FUSE) {
          const size_t off = (size_t)row * N + col;
          Cf[off] = v + resid[off];
        } else {
          Cbf[(size_t)row * ldc + col] = (bf16)v;
        }
      }
    }
  }
}

// ---------------- flash attention: block = (b, h, 64 q-rows), 4 waves x 16 rows ----------------
// K staged from qkv rows; V staged from pre-transposed Vt. Padded LDS strides kill bank conflicts.
// Output written into qkv's (dead) V columns: out base = qkv + 2*D_, row stride 3*D_.
__global__ __launch_bounds__(256) void attn64(const bf16* __restrict__ qkv,
                                              const bf16* __restrict__ Vt,
                                              bf16* __restrict__ out) {
  __shared__ alignas(16) bf16 Ks[128 * 72];      // [key][f], stride 72 (pad: 144B rows)
  __shared__ alignas(16) bf16 Vs[64 * 136];      // [f][key], stride 136 (pad: 272B rows)
  __shared__ alignas(16) bf16 Ps[4 * 16 * 136];  // per-wave P [16][128], stride 136
  const int tid = threadIdx.x;
  const int wid = tid >> 6, lane = tid & 63, quad = lane >> 4, l16 = lane & 15;
  int bid = blockIdx.x;
  const int qb = bid & 31; bid >>= 5;
  const int h = bid & 15;  const int b = bid >> 4;
  const int q0 = qb * 64;

  // Q fragments (A-operand layout: m=lane&15, k=quad*8+j), 2 k-steps of 32
  bf16x8 qf[2];
  {
    const bf16* qp = qkv + (size_t)(b * T_ + q0 + wid * 16 + l16) * (3 * D_) + h * DK_ + quad * 8;
    qf[0] = *(const bf16x8*)qp;
    qf[1] = *(const bf16x8*)(qp + 32);
  }

  float mi[4], li[4];
  f32x4 o[4];
#pragma unroll
  for (int r = 0; r < 4; ++r) { mi[r] = -1e30f; li[r] = 0.f; }
#pragma unroll
  for (int ft = 0; ft < 4; ++ft) o[ft] = zero4();

  for (int kt = 0; kt < T_ / 128; ++kt) {
    __syncthreads();
#pragma unroll
    for (int p = 0; p < 4; ++p) {
      int t = p * 256 + tid;            // [0,1024)
      int key = t >> 3, f = (t & 7) * 8;
      *(bf16x8*)&Ks[key * 72 + f] =
          *(const bf16x8*)(qkv + (size_t)(b * T_ + kt * 128 + key) * (3 * D_) + D_ + h * DK_ + f);
      int vf = t >> 4, kc = (t & 15) * 8;
      *(bf16x8*)&Vs[vf * 136 + kc] =
          *(const bf16x8*)(Vt + ((size_t)(b * H_ + h) * DK_ + vf) * T_ + kt * 128 + kc);
    }
    __syncthreads();

    // S = scale * Q K^T : per wave 16 x 128
    f32x4 sv[8];
#pragma unroll
    for (int nt = 0; nt < 8; ++nt) sv[nt] = zero4();
#pragma unroll
    for (int nt = 0; nt < 8; ++nt)
#pragma unroll
      for (int ks = 0; ks < 2; ++ks) {
        bf16x8 kf = *(const bf16x8*)&Ks[(nt * 16 + l16) * 72 + ks * 32 + quad * 8];
        sv[nt] = __builtin_amdgcn_mfma_f32_16x16x32_bf16(qf[ks], kf, sv[nt], 0, 0, 0);
      }

    // online softmax per row (row = quad*4 + r, cols spread over 16 lanes of the quad)
    float alpha[4];
#pragma unroll
    for (int r = 0; r < 4; ++r) {
      float tmax = -1e30f;
#pragma unroll
      for (int nt = 0; nt < 8; ++nt) { sv[nt][r] *= 0.125f; tmax = fmaxf(tmax, sv[nt][r]); }
#pragma unroll
      for (int m = 1; m < 16; m <<= 1) tmax = fmaxf(tmax, __shfl_xor(tmax, m, 64));
      const float mnew = fmaxf(mi[r], tmax);
      alpha[r] = __expf(mi[r] - mnew);
      float s = 0.f;
#pragma unroll
      for (int nt = 0; nt < 8; ++nt) {
        float pe = __expf(sv[nt][r] - mnew);
        sv[nt][r] = pe; s += pe;
      }
#pragma unroll
      for (int m = 1; m < 16; m <<= 1) s += __shfl_xor(s, m, 64);
      li[r] = li[r] * alpha[r] + s;
      mi[r] = mnew;
#pragma unroll
      for (int ft = 0; ft < 4; ++ft) o[ft][r] *= alpha[r];
    }

    // P: C-layout -> A-layout via LDS (per-wave private region)
#pragma unroll
    for (int nt = 0; nt < 8; ++nt)
#pragma unroll
      for (int r = 0; r < 4; ++r)
        Ps[wid * 2176 + (quad * 4 + r) * 136 + nt * 16 + l16] = (bf16)sv[nt][r];
    __syncthreads();

    // O += P @ V  (B-operand from Vs = V^T tile)
#pragma unroll
    for (int ks2 = 0; ks2 < 4; ++ks2) {
      bf16x8 pf = *(const bf16x8*)&Ps[wid * 2176 + l16 * 136 + ks2 * 32 + quad * 8];
#pragma unroll
      for (int ft = 0; ft < 4; ++ft) {
        bf16x8 vfr = *(const bf16x8*)&Vs[(ft * 16 + l16) * 136 + ks2 * 32 + quad * 8];
        o[ft] = __builtin_amdgcn_mfma_f32_16x16x32_bf16(pf, vfr, o[ft], 0, 0, 0);
      }
    }
  }

#pragma unroll
  for (int r = 0; r < 4; ++r) {
    const float inv = 1.0f / li[r];
    const int row = b * T_ + q0 + wid * 16 + quad * 4 + r;
#pragma unroll
    for (int ft = 0; ft < 4; ++ft)
      out[(size_t)row * (3 * D_) + h * DK_ + ft * 16 + l16] = (bf16)(o[ft][r] * inv);
  }
}

// ---------------- layernorm: one block per row, in-place on fp32 buffer ----------------
__global__ __launch_bounds__(256) void ln_out(float* __restrict__ res,
                                              const float* __restrict__ gamma,
                                              const float* __restrict__ beta) {
  const int row = blockIdx.x;
  const int tid = threadIdx.x;
  const float4 v = *(const float4*)(res + (size_t)row * D_ + tid * 4);
  float s = v.x + v.y + v.z + v.w;
  float q = v.x * v.x + v.y * v.y + v.z * v.z + v.w * v.w;
#pragma unroll
  for (int m = 1; m < 64; m <<= 1) { s += __shfl_xor(s, m, 64); q += __shfl_xor(q, m, 64); }
  __shared__ float rs_[4], rq_[4];
  const int wid = tid >> 6, lane = tid & 63;
  if (lane == 0) { rs_[wid] = s; rq_[wid] = q; }
  __syncthreads();
  s = rs_[0] + rs_[1] + rs_[2] + rs_[3];
  q = rq_[0] + rq_[1] + rq_[2] + rq_[3];
  const float mu = s * (1.0f / D_);
  const float var = q * (1.0f / D_) - mu * mu;
  const float rstd = rsqrtf(var + 1e-5f);
  const float* vp = (const float*)&v;
  float4 ov;
  float* ovp = (float*)&ov;
#pragma unroll
  for (int i = 0; i < 4; ++i) {
    const int c = tid * 4 + i;
    ovp[i] = ((vp[i] - mu) * rstd) * gamma[c] + beta[c];
  }
  *(float4*)(res + (size_t)row * D_ + tid * 4) = ov;
}

extern "C" void kernel_launch(void* const* d_in, const int* in_sizes, int n_in,
                              void* d_out, int out_size, void* d_ws, size_t ws_size,
                              hipStream_t stream) {
  const float* x     = (const float*)d_in[0];
  const float* Wqkv  = (const float*)d_in[1];
  const float* bqkv  = (const float*)d_in[2];
  const float* Wout  = (const float*)d_in[3];
  const float* bout  = (const float*)d_in[4];
  const float* gamma = (const float*)d_in[5];
  const float* beta  = (const float*)d_in[6];
  float* out = (float*)d_out;  // also used as the fp32 residual buffer (LN in-place)

  // workspace layout (75.5 MB, same footprint as the passing round):
  char* ws = (char*)d_ws;
  bf16* WqkvT = (bf16*)ws; ws += (size_t)3 * D_ * D_ * 2;        // [3072][1024]   6.3 MB
  bf16* WoutT = (bf16*)ws; ws += (size_t)D_ * D_ * 2;            // [1024][1024]   2.1 MB
  bf16* qkv   = (bf16*)ws; ws += (size_t)M_ * 3 * D_ * 2;        // [8192][3072]  50.3 MB
  bf16* Vt    = (bf16*)ws;                                       // [4][16][64][2048] 16.8 MB
  bf16* attn  = qkv + 2 * D_;  // attn output overwrites qkv's V columns (dead after transpose_v)

  transpose_wf<<<dim3(D_ / 64, 3 * D_ / 64), 256, 0, stream>>>(Wqkv, WqkvT, D_, 3 * D_);
  transpose_wf<<<dim3(D_ / 64, D_ / 64), 256, 0, stream>>>(Wout, WoutT, D_, D_);
  gemm128<true, false><<<dim3(M_ / 128, 3 * D_ / 128), 256, 0, stream>>>(
      x, WqkvT, bqkv, qkv, nullptr, nullptr, 3 * D_, D_, D_, 3 * D_);
  transpose_v<<<B_ * H_ * (T_ / 64), 256, 0, stream>>>(qkv, Vt);
  attn64<<<B_ * H_ * (T_ / 64), 256, 0, stream>>>(qkv, Vt, attn);
  gemm128<false, true><<<dim3(M_ / 128, D_ / 128), 256, 0, stream>>>(
      attn, WoutT, bout, nullptr, out, x, D_, D_, 3 * D_, D_);
  ln_out<<<M_, 256, 0, stream>>>(out, gamma, beta);
}

// Round 6
// 388.599 us; speedup vs baseline: 1.5732x; 1.2413x over previous
//
#include <hip/hip_runtime.h>

#define B_ 4
#define T_ 2048
#define D_ 1024
#define H_ 16
#define DK_ 64
#define M_ (B_*T_)   // 8192 rows

typedef __bf16 bf16;
typedef __bf16 bf16x8 __attribute__((ext_vector_type(8)));
typedef __bf16 bf16x4 __attribute__((ext_vector_type(4)));
typedef short s16x4 __attribute__((ext_vector_type(4)));
typedef float f32x4 __attribute__((ext_vector_type(4)));

__device__ __forceinline__ f32x4 zero4() { f32x4 v = {0.f, 0.f, 0.f, 0.f}; return v; }

// async global->LDS, 16B per lane; LDS base wave-uniform, HW adds lane*16
__device__ __forceinline__ void g2l16(const void* g, void* l) {
  __builtin_amdgcn_global_load_lds(
      (const __attribute__((address_space(1))) void*)g,
      (__attribute__((address_space(3))) void*)l, 16, 0, 0);
}

// ---------------- weight transpose + cast: dst[C][R] = (bf16)src[R][C] ----------------
__global__ __launch_bounds__(256) void transpose_wf(const float* __restrict__ src,
                                                    bf16* __restrict__ dst, int R, int C) {
  __shared__ alignas(16) bf16 ts[64 * 65];
  const int tid = threadIdx.x;
  const int r0 = blockIdx.x * 64, c0 = blockIdx.y * 64;
  {
    int rr = tid >> 2, cc = (tid & 3) * 16;
    const float4* p4 = (const float4*)(src + (size_t)(r0 + rr) * C + c0 + cc);
    float fv[16];
#pragma unroll
    for (int q = 0; q < 4; ++q) *(float4*)&fv[q * 4] = p4[q];
#pragma unroll
    for (int i = 0; i < 16; ++i) ts[(cc + i) * 65 + rr] = (bf16)fv[i];
  }
  __syncthreads();
  {
    int rr = tid >> 2, cc = (tid & 3) * 16;
    bf16x8 a, b;
#pragma unroll
    for (int i = 0; i < 8; ++i) a[i] = ts[rr * 65 + cc + i];
#pragma unroll
    for (int i = 0; i < 8; ++i) b[i] = ts[rr * 65 + cc + 8 + i];
    bf16* q = dst + (size_t)(c0 + rr) * R + r0 + cc;
    *(bf16x8*)q = a;
    *(bf16x8*)(q + 8) = b;
  }
}

// ---------------- V transpose: Vt[b][h][f][t] = qkv[b*T+t][2D + h*64 + f] ----------------
__global__ __launch_bounds__(256) void transpose_v(const bf16* __restrict__ qkv,
                                                   bf16* __restrict__ Vt) {
  __shared__ alignas(16) bf16 ts[64 * 65];
  int bid = blockIdx.x;
  const int tt = bid & 31; bid >>= 5;
  const int h = bid & 15;  const int b = bid >> 4;
  const int t0 = tt * 64;
  const int tid = threadIdx.x;
  {
    int tok = tid >> 2, fc = (tid & 3) * 16;
    const bf16* p = qkv + (size_t)(b * T_ + t0 + tok) * (3 * D_) + 2 * D_ + h * DK_ + fc;
    bf16x8 a = *(const bf16x8*)p;
    bf16x8 c = *(const bf16x8*)(p + 8);
#pragma unroll
    for (int i = 0; i < 8; ++i) ts[(fc + i) * 65 + tok] = a[i];
#pragma unroll
    for (int i = 0; i < 8; ++i) ts[(fc + 8 + i) * 65 + tok] = c[i];
  }
  __syncthreads();
  {
    int f = tid >> 2, tc = (tid & 3) * 16;
    bf16x8 a, c;
#pragma unroll
    for (int i = 0; i < 8; ++i) a[i] = ts[f * 65 + tc + i];
#pragma unroll
    for (int i = 0; i < 8; ++i) c[i] = ts[f * 65 + tc + 8 + i];
    bf16* q = Vt + ((size_t)(b * H_ + h) * DK_ + f) * T_ + t0 + tc;
    *(bf16x8*)q = a;
    *(bf16x8*)(q + 8) = c;
  }
}

// ---------------- GEMM: C[M][N] = A[M][K] @ Bt[N][K]^T + bias ----------------
// ASRC=0: A fp32, cast during register staging. ASRC=1: A bf16, DMA-staged.
// B always DMA-staged (m97 pattern). FUSE: Cf32 = C + resid(fp32), stride N.
template <int ASRC, bool FUSE>
__global__ __launch_bounds__(256) void gemm128(const void* __restrict__ Av,
                                               const bf16* __restrict__ Bt,
                                               const float* __restrict__ bias,
                                               bf16* __restrict__ Cbf,
                                               float* __restrict__ Cf,
                                               const float* __restrict__ resid,
                                               int N, int K, int lda, int ldc) {
  __shared__ alignas(16) bf16 As[128 * 32];
  __shared__ alignas(16) bf16 Bs[128 * 32];
  const int tid = threadIdx.x;
  const int wid = tid >> 6, lane = tid & 63, quad = lane >> 4, l16 = lane & 15;
  const int m0 = blockIdx.x * 128, n0 = blockIdx.y * 128;
  const int wr = (wid >> 1) * 64, wc = (wid & 1) * 64;

  f32x4 acc[4][4];
#pragma unroll
  for (int i = 0; i < 4; ++i)
#pragma unroll
    for (int j = 0; j < 4; ++j) acc[i][j] = zero4();

  for (int k0 = 0; k0 < K; k0 += 32) {
    bf16x8 ar[2];
    if (ASRC == 0) {
#pragma unroll
      for (int p = 0; p < 2; ++p) {
        int t = p * 256 + tid;
        int row = t >> 2, kc = (t & 3) * 8;
        const float* ap = (const float*)Av + (size_t)(m0 + row) * lda + k0 + kc;
        float4 a0 = *(const float4*)ap, a1 = *(const float4*)(ap + 4);
        bf16x8 v;
        v[0] = (bf16)a0.x; v[1] = (bf16)a0.y; v[2] = (bf16)a0.z; v[3] = (bf16)a0.w;
        v[4] = (bf16)a1.x; v[5] = (bf16)a1.y; v[6] = (bf16)a1.z; v[7] = (bf16)a1.w;
        ar[p] = v;
      }
    }
    __syncthreads();  // previous iteration's LDS reads complete
#pragma unroll
    for (int p = 0; p < 2; ++p) {
      int t = p * 256 + tid;
      int row = t >> 2, kc = (t & 3) * 8;
      g2l16(Bt + (size_t)(n0 + row) * K + k0 + kc, (char*)Bs + p * 4096 + wid * 1024);
      if (ASRC == 1)
        g2l16((const bf16*)Av + (size_t)(m0 + row) * lda + k0 + kc,
              (char*)As + p * 4096 + wid * 1024);
      else
        *(bf16x8*)&As[row * 32 + kc] = ar[p];
    }
    __syncthreads();
    bf16x8 af[4], bfr[4];
#pragma unroll
    for (int i = 0; i < 4; ++i)
      af[i] = *(const bf16x8*)&As[(wr + i * 16 + l16) * 32 + quad * 8];
#pragma unroll
    for (int j = 0; j < 4; ++j)
      bfr[j] = *(const bf16x8*)&Bs[(wc + j * 16 + l16) * 32 + quad * 8];
#pragma unroll
    for (int i = 0; i < 4; ++i)
#pragma unroll
      for (int j = 0; j < 4; ++j)
        acc[i][j] = __builtin_amdgcn_mfma_f32_16x16x32_bf16(af[i], bfr[j], acc[i][j], 0, 0, 0);
  }

#pragma unroll
  for (int i = 0; i < 4; ++i) {
#pragma unroll
    for (int j = 0; j < 4; ++j) {
      const int col = n0 + wc + j * 16 + l16;
      const float bv = bias[col];
#pragma unroll
      for (int r = 0; r < 4; ++r) {
        const int row = m0 + wr + i * 16 + quad * 4 + r;
        const float v = acc[i][j][r] + bv;
        if (FUSE) {
          const size_t off = (size_t)row * N + col;
          Cf[off] = v + resid[off];
        } else {
          Cbf[(size_t)row * ldc + col] = (bf16)v;
        }
      }
    }
  }
}

// ---------------- flash attention: block = (b, h, 64 q-rows), 4 waves x 16 rows ----------------
// S^T = K Q^T via 16x16x32 (C-layout row=key, col=qrow). P stays in registers and feeds
// O = P V via 16x16x16 (A-operand k=quad*4+j == S^T C-layout rows). No P LDS round-trip.
__global__ __launch_bounds__(256) void attn64(const bf16* __restrict__ qkv,
                                              const bf16* __restrict__ Vt,
                                              bf16* __restrict__ out) {
  __shared__ alignas(16) bf16 Ks[128 * 72];      // [key][f], stride 72 (144B rows: aligned, 2-way free)
  __shared__ alignas(16) bf16 Vs[64 * 136];      // [f][key], stride 136 (272B rows)
  const int tid = threadIdx.x;
  const int wid = tid >> 6, lane = tid & 63, quad = lane >> 4, l16 = lane & 15;
  int bid = blockIdx.x;
  const int qb = bid & 31; bid >>= 5;
  const int h = bid & 15;  const int b = bid >> 4;
  const int q0 = qb * 64;

  // Q fragments as MFMA **B-operand** (k=quad*8+j, n=qrow=l16), pre-scaled by 1/8 (exact in bf16)
  bf16x8 qf[2];
  {
    const bf16* qp = qkv + (size_t)(b * T_ + q0 + wid * 16 + l16) * (3 * D_) + h * DK_ + quad * 8;
    qf[0] = *(const bf16x8*)qp;
    qf[1] = *(const bf16x8*)(qp + 32);
#pragma unroll
    for (int i = 0; i < 8; ++i) { qf[0][i] = (bf16)((float)qf[0][i] * 0.125f);
                                  qf[1][i] = (bf16)((float)qf[1][i] * 0.125f); }
  }

  float mi = -1e30f, li = 0.f;   // per-lane: qrow = l16 (replicated across quads)
  f32x4 o[4];                    // o[ft][r] = O[qrow=quad*4+r][f=ft*16+l16]
#pragma unroll
  for (int ft = 0; ft < 4; ++ft) o[ft] = zero4();

  for (int kt = 0; kt < T_ / 128; ++kt) {
    __syncthreads();
#pragma unroll
    for (int p = 0; p < 4; ++p) {
      int t = p * 256 + tid;            // [0,1024)
      int key = t >> 3, f = (t & 7) * 8;
      *(bf16x8*)&Ks[key * 72 + f] =
          *(const bf16x8*)(qkv + (size_t)(b * T_ + kt * 128 + key) * (3 * D_) + D_ + h * DK_ + f);
      int vf = t >> 4, kc = (t & 15) * 8;
      *(bf16x8*)&Vs[vf * 136 + kc] =
          *(const bf16x8*)(Vt + ((size_t)(b * H_ + h) * DK_ + vf) * T_ + kt * 128 + kc);
    }
    __syncthreads();

    // S^T tile: sv[nt] reg r = S[key = nt*16 + quad*4 + r][qrow = l16]
    f32x4 sv[8];
#pragma unroll
    for (int nt = 0; nt < 8; ++nt) sv[nt] = zero4();
#pragma unroll
    for (int nt = 0; nt < 8; ++nt)
#pragma unroll
      for (int ks = 0; ks < 2; ++ks) {
        bf16x8 kf = *(const bf16x8*)&Ks[(nt * 16 + l16) * 72 + ks * 32 + quad * 8];
        sv[nt] = __builtin_amdgcn_mfma_f32_16x16x32_bf16(kf, qf[ks], sv[nt], 0, 0, 0);
      }

    // online softmax: each lane owns 32 scores of qrow=l16; reduce in-lane + across quads
    float tmax = mi;
#pragma unroll
    for (int nt = 0; nt < 8; ++nt)
#pragma unroll
      for (int r = 0; r < 4; ++r) tmax = fmaxf(tmax, sv[nt][r]);
    tmax = fmaxf(tmax, __shfl_xor(tmax, 16, 64));
    tmax = fmaxf(tmax, __shfl_xor(tmax, 32, 64));
    const float alpha = __expf(mi - tmax);
    mi = tmax;
    float s = 0.f;
#pragma unroll
    for (int nt = 0; nt < 8; ++nt)
#pragma unroll
      for (int r = 0; r < 4; ++r) {
        float pe = __expf(sv[nt][r] - tmax);
        sv[nt][r] = pe; s += pe;
      }
    s += __shfl_xor(s, 16, 64);
    s += __shfl_xor(s, 32, 64);
    li = li * alpha + s;

    // rescale O: o[ft][r] holds qrow=quad*4+r -> fetch that row's alpha (lives at lane quad*4+r)
#pragma unroll
    for (int r = 0; r < 4; ++r) {
      const float ar = __shfl(alpha, quad * 4 + r, 64);
#pragma unroll
      for (int ft = 0; ft < 4; ++ft) o[ft][r] *= ar;
    }

    // O += P V via 16x16x16: A = P from registers (k=key=ks*16+quad*4+j == sv[ks] regs)
#pragma unroll
    for (int ks = 0; ks < 8; ++ks) {
      union { bf16x4 b; s16x4 s; } pf;
#pragma unroll
      for (int j = 0; j < 4; ++j) pf.b[j] = (bf16)sv[ks][j];
#pragma unroll
      for (int ft = 0; ft < 4; ++ft) {
        const s16x4 vf = *(const s16x4*)&Vs[(ft * 16 + l16) * 136 + ks * 16 + quad * 4];
        o[ft] = __builtin_amdgcn_mfma_f32_16x16x16bf16_1k(pf.s, vf, o[ft], 0, 0, 0);
      }
    }
  }

  // epilogue: normalize rows (li for qrow=quad*4+r lives at lane quad*4+r)
#pragma unroll
  for (int r = 0; r < 4; ++r) {
    const float inv = 1.0f / __shfl(li, quad * 4 + r, 64);
    const int row = b * T_ + q0 + wid * 16 + quad * 4 + r;
#pragma unroll
    for (int ft = 0; ft < 4; ++ft)
      out[(size_t)row * (3 * D_) + h * DK_ + ft * 16 + l16] = (bf16)(o[ft][r] * inv);
  }
}

// ---------------- layernorm: one block per row, in-place on fp32 buffer ----------------
__global__ __launch_bounds__(256) void ln_out(float* __restrict__ res,
                                              const float* __restrict__ gamma,
                                              const float* __restrict__ beta) {
  const int row = blockIdx.x;
  const int tid = threadIdx.x;
  const float4 v = *(const float4*)(res + (size_t)row * D_ + tid * 4);
  float s = v.x + v.y + v.z + v.w;
  float q = v.x * v.x + v.y * v.y + v.z * v.z + v.w * v.w;
#pragma unroll
  for (int m = 1; m < 64; m <<= 1) { s += __shfl_xor(s, m, 64); q += __shfl_xor(q, m, 64); }
  __shared__ float rs_[4], rq_[4];
  const int wid = tid >> 6, lane = tid & 63;
  if (lane == 0) { rs_[wid] = s; rq_[wid] = q; }
  __syncthreads();
  s = rs_[0] + rs_[1] + rs_[2] + rs_[3];
  q = rq_[0] + rq_[1] + rq_[2] + rq_[3];
  const float mu = s * (1.0f / D_);
  const float var = q * (1.0f / D_) - mu * mu;
  const float rstd = rsqrtf(var + 1e-5f);
  const float* vp = (const float*)&v;
  float4 ov;
  float* ovp = (float*)&ov;
#pragma unroll
  for (int i = 0; i < 4; ++i) {
    const int c = tid * 4 + i;
    ovp[i] = ((vp[i] - mu) * rstd) * gamma[c] + beta[c];
  }
  *(float4*)(res + (size_t)row * D_ + tid * 4) = ov;
}

extern "C" void kernel_launch(void* const* d_in, const int* in_sizes, int n_in,
                              void* d_out, int out_size, void* d_ws, size_t ws_size,
                              hipStream_t stream) {
  const float* x     = (const float*)d_in[0];
  const float* Wqkv  = (const float*)d_in[1];
  const float* bqkv  = (const float*)d_in[2];
  const float* Wout  = (const float*)d_in[3];
  const float* bout  = (const float*)d_in[4];
  const float* gamma = (const float*)d_in[5];
  const float* beta  = (const float*)d_in[6];
  float* out = (float*)d_out;  // also the fp32 residual buffer (LN in-place)

  // workspace layout (75.5 MB):
  char* ws = (char*)d_ws;
  bf16* WqkvT = (bf16*)ws; ws += (size_t)3 * D_ * D_ * 2;        // [3072][1024]
  bf16* WoutT = (bf16*)ws; ws += (size_t)D_ * D_ * 2;            // [1024][1024]
  bf16* qkv   = (bf16*)ws; ws += (size_t)M_ * 3 * D_ * 2;        // [8192][3072]
  bf16* Vt    = (bf16*)ws;                                       // [4][16][64][2048]
  bf16* attn  = qkv + 2 * D_;  // attn output overwrites qkv's V columns (dead after transpose_v)

  transpose_wf<<<dim3(D_ / 64, 3 * D_ / 64), 256, 0, stream>>>(Wqkv, WqkvT, D_, 3 * D_);
  transpose_wf<<<dim3(D_ / 64, D_ / 64), 256, 0, stream>>>(Wout, WoutT, D_, D_);
  gemm128<0, false><<<dim3(M_ / 128, 3 * D_ / 128), 256, 0, stream>>>(
      x, WqkvT, bqkv, qkv, nullptr, nullptr, 3 * D_, D_, D_, 3 * D_);
  transpose_v<<<B_ * H_ * (T_ / 64), 256, 0, stream>>>(qkv, Vt);
  attn64<<<B_ * H_ * (T_ / 64), 256, 0, stream>>>(qkv, Vt, attn);
  gemm128<1, true><<<dim3(M_ / 128, D_ / 128), 256, 0, stream>>>(
      attn, WoutT, bout, nullptr, out, x, D_, D_, 3 * D_, D_);
  ln_out<<<M_, 256, 0, stream>>>(out, gamma, beta);
}